// Round 13
// baseline (5027.017 us; speedup 1.0000x reference)
//
#include <hip/hip_runtime.h>

typedef _Float16 half8 __attribute__((ext_vector_type(8)));
typedef float f32x4 __attribute__((ext_vector_type(4)));
typedef float f32x2 __attribute__((ext_vector_type(2)));

#define BB 64
#define SS 512
#define DD 512
#define HH 1024
#define KK 1536
#define NBLK 64

#define MFMA(a, b, c) __builtin_amdgcn_mfma_f32_16x16x32_f16(a, b, c, 0, 0, 0)

// x-region of Wp: fragment permutation; h-region: identity on both operands
// (the shared permutation cancels inside the MFMA dot product).
__device__ __host__ __forceinline__ int kperm(int k) {
  int blk = k >> 5, r = k & 31;
  return (blk << 5) | (((r >> 2) & 3) << 3) | ((r >> 4) << 2) | (r & 3);
}

// Pack weights: Wp[p][k'] fp16, p = b*80 + tile*16 + c  (tile: 0=g,1=r,2=z,3=i_n,4=h_n)
__global__ void prep_w(const float* __restrict__ Wg, const float* __restrict__ Wih,
                       const float* __restrict__ Whh, _Float16* __restrict__ Wp) {
  int p = blockIdx.x;
  int b = p / 80, rem = p % 80, t = rem >> 4, c = rem & 15;
  int j = b * 16 + c;
  for (int pass = 0; pass < 6; ++pass) {
    int k = pass * 256 + threadIdx.x;
    float v;
    if (t == 0)      v = Wg[k * HH + j];
    else if (t == 1) v = (k < DD) ? Wih[k * 3 * HH + j]          : Whh[(k - DD) * 3 * HH + j];
    else if (t == 2) v = (k < DD) ? Wih[k * 3 * HH + HH + j]     : Whh[(k - DD) * 3 * HH + HH + j];
    else if (t == 3) v = (k < DD) ? Wih[k * 3 * HH + 2 * HH + j] : 0.f;
    else             v = (k < DD) ? 0.f : Whh[(k - DD) * 3 * HH + 2 * HH + j];
    int pos = (k < DD) ? kperm(k) : k;      // x: kperm'd, h: identity
    Wp[(size_t)p * KK + pos] = (_Float16)v;
  }
}

// Xh[t][sg][row][lkg][8]: fp16 x in fragment-ready order (sg = x k-step 0..15)
__global__ void prep_xh(const float* __restrict__ x, _Float16* __restrict__ Xh) {
  int t = blockIdx.x, sg = blockIdx.y;
  int row = threadIdx.x >> 2, lkg = threadIdx.x & 3;
  const float* xp = x + ((size_t)row * SS + t) * DD + sg * 32 + lkg * 4;
  half8 hv;
#pragma unroll
  for (int j = 0; j < 4; ++j) { hv[j] = (_Float16)xp[j]; hv[4 + j] = (_Float16)xp[16 + j]; }
  *(half8*)(Xh + ((((size_t)t * 16 + sg) * 64 + row) * 4 + lkg) * 8) = hv;
}

#define WAITV(lit) do { asm volatile("s_waitcnt vmcnt(" lit ")" ::: "memory"); \
                        __builtin_amdgcn_sched_barrier(0); } while (0)

// H exchange buffer layout (THE one change vs r12):
//   Hbuf2[parity][producer p][row 0..63][16 halfs]  -- producer-contiguous.
// Producer blk's per-step publish = one contiguous 2KB region (32 full 64B
// lines, two fully-coalesced 1KB store instructions, no partial-line RMW).
// Consumer fragment (w, kk, lkg) reads the SAME 16 bytes as the old
// row-major layout: col offset 8*lkg == 16*(lkg>>1) + 8*(lkg&1), so
// p = (w*4+kk)*2 + (lkg>>1), half = (lkg&1)*8. Identity-cancellation with
// the B-side (Wp h-region) is untouched.

__global__ __launch_bounds__(512, 2) void rnn_seq(
    const _Float16* __restrict__ Xh, const _Float16* __restrict__ Wp,
    const float* __restrict__ bg, const float* __restrict__ bih,
    const float* __restrict__ bhh, float* __restrict__ out,
    _Float16* __restrict__ Hbuf, unsigned* __restrict__ flags) {
  const int blk = blockIdx.x;
  const int tid = threadIdx.x;
  const int w = tid >> 6;              // wave 0..7
  const int lane = tid & 63;
  const int lrow = lane & 15;
  const int lkg = lane >> 4;
  const int phalf = lkg >> 1;          // producer parity within k-step
  const int chalf = (lkg & 1) * 8;     // 8-col half within producer region

  __shared__ float Red[4][80][68];               // 87,040 B
  __shared__ alignas(16) _Float16 Hst[64][16];   //  2,048 B
  __shared__ alignas(16) _Float16 Xstage[64 * 512];  // 65,536 B

  const int ej = tid & 15;
  const int rpp = tid >> 4;            // 0..31
  const int ghcol = blk * 16 + ej;
  const float bg_b  = bg[ghcol];
  const float br_b  = bih[ghcol] + bhh[ghcol];
  const float bz_b  = bih[HH + ghcol] + bhh[HH + ghcol];
  const float bin_b = bih[2 * HH + ghcol];
  const float bhn_b = bhh[2 * HH + ghcol];
  float hreg[2] = {0.f, 0.f};

  // wave w consumes h cols [w*128, w*128+128) -> producers 8w .. 8w+7 only
  const int myprod = 8 * w + (lane & 7);

  // register-resident weights (24 half8 = 96 VGPR), r5 layout
  half8 bx[3][2], b3[2], bh[3][4], b4[4];
#pragma unroll
  for (int tt = 0; tt < 3; ++tt)
#pragma unroll
    for (int kk = 0; kk < 2; ++kk)
      bx[tt][kk] = *(const half8*)(Wp + (size_t)(blk * 80 + tt * 16 + lrow) * KK + (w * 2 + kk) * 32 + lkg * 8);
#pragma unroll
  for (int kk = 0; kk < 2; ++kk)
    b3[kk] = *(const half8*)(Wp + (size_t)(blk * 80 + 48 + lrow) * KK + (w * 2 + kk) * 32 + lkg * 8);
#pragma unroll
  for (int tt = 0; tt < 3; ++tt)
#pragma unroll
    for (int kk = 0; kk < 4; ++kk)
      bh[tt][kk] = *(const half8*)(Wp + (size_t)(blk * 80 + tt * 16 + lrow) * KK + (16 + w * 4 + kk) * 32 + lkg * 8);
#pragma unroll
  for (int kk = 0; kk < 4; ++kk)
    b4[kk] = *(const half8*)(Wp + (size_t)(blk * 80 + 64 + lrow) * KK + (16 + w * 4 + kk) * 32 + lkg * 8);

  // prefetch Xstage(t=0)
#pragma unroll
  for (int kk = 0; kk < 2; ++kk)
#pragma unroll
    for (int mt = 0; mt < 4; ++mt) {
      const _Float16* gsrc = Xh + ((((size_t)0 * 16 + (w * 2 + kk)) * 64 + (mt * 16 + lrow)) * 4 + lkg) * 8;
      __builtin_amdgcn_global_load_lds(
          (const __attribute__((address_space(1))) void*)gsrc,
          (__attribute__((address_space(3))) void*)(Xstage + (w * 8 + kk * 4 + mt) * 512), 16, 0, 0);
    }
  WAITV("0");

  for (int t = 0; t < SS; ++t) {
    const _Float16* Hb = Hbuf + (size_t)(t & 1) * (BB * HH);
    _Float16* Hn = Hbuf + (size_t)((t + 1) & 1) * (BB * HH);

    f32x4 zz = {0.f, 0.f, 0.f, 0.f};
    f32x4 acc[5][4];
#pragma unroll
    for (int tt = 0; tt < 5; ++tt)
#pragma unroll
      for (int mt = 0; mt < 4; ++mt) acc[tt][mt] = zz;

    // ---- x ds_reads into registers (Xstage(t) resident via prev drain) ----
    half8 xfr[2][4];
#pragma unroll
    for (int kk = 0; kk < 2; ++kk)
#pragma unroll
      for (int mt = 0; mt < 4; ++mt)
        xfr[kk][mt] = *(const half8*)(Xstage + (w * 8 + kk * 4 + mt) * 512 + lane * 8);
    asm volatile("s_waitcnt lgkmcnt(0)" ::: "memory");   // reads retired (WAR)
    __builtin_amdgcn_sched_barrier(0);

    // ---- xpref(t+1): issued BEFORE the poll; latency hides under the wait
    {
      const int tn = (t + 1 < SS) ? t + 1 : t;
#pragma unroll
      for (int kk = 0; kk < 2; ++kk)
#pragma unroll
        for (int mt = 0; mt < 4; ++mt) {
          const _Float16* gsrc = Xh + ((((size_t)tn * 16 + (w * 2 + kk)) * 64 + (mt * 16 + lrow)) * 4 + lkg) * 8;
          __builtin_amdgcn_global_load_lds(
              (const __attribute__((address_space(1))) void*)gsrc,
              (__attribute__((address_space(3))) void*)(Xstage + (w * 8 + kk * 4 + mt) * 512), 16, 0, 0);
        }
    }

    // ---- per-wave poll: wait ONLY on this wave's 8 producers (fan-in 8);
    // poll-load retirement also drains xpref -> queue empty at ha issue.
    for (;;) {
      unsigned v = __hip_atomic_load(&flags[myprod], __ATOMIC_RELAXED, __HIP_MEMORY_SCOPE_AGENT);
      if (__all((int)(v >= (unsigned)t))) break;
      __builtin_amdgcn_s_sleep(1);
    }
    __builtin_amdgcn_sched_barrier(0);

    // ---- issue both h batches (producer-contiguous addressing);
    // x-MFMA below hides their latency ----
    half8 ha[2][4], hb[2][4];
#pragma unroll
    for (int kk = 0; kk < 2; ++kk)
#pragma unroll
      for (int mt = 0; mt < 4; ++mt) {
        const int p = (w * 4 + kk) * 2 + phalf;
        const _Float16* hp = Hb + ((size_t)(p * 64 + mt * 16 + lrow) * 16 + chalf);
        asm volatile("global_load_dwordx4 %0, %1, off sc0 sc1"
                     : "=&v"(ha[kk][mt]) : "v"(hp) : "memory");
      }
#pragma unroll
    for (int kk = 0; kk < 2; ++kk)
#pragma unroll
      for (int mt = 0; mt < 4; ++mt) {
        const int p = (w * 4 + 2 + kk) * 2 + phalf;
        const _Float16* hp = Hb + ((size_t)(p * 64 + mt * 16 + lrow) * 16 + chalf);
        asm volatile("global_load_dwordx4 %0, %1, off sc0 sc1"
                     : "=&v"(hb[kk][mt]) : "v"(hp) : "memory");
      }

    // ---- x-MFMA from registers (overlaps h-load round trip) ----
#pragma unroll
    for (int kk = 0; kk < 2; ++kk)
#pragma unroll
      for (int mt = 0; mt < 4; ++mt) {
        acc[0][mt] = MFMA(xfr[kk][mt], bx[0][kk], acc[0][mt]);
        acc[1][mt] = MFMA(xfr[kk][mt], bx[1][kk], acc[1][mt]);
        acc[2][mt] = MFMA(xfr[kk][mt], bx[2][kk], acc[2][mt]);
        acc[3][mt] = MFMA(xfr[kk][mt], b3[kk], acc[3][mt]);
      }

    // ---- h-MFMA: counted waits (queue exactly [ha:8][hb:8] here) ----
    WAITV("8");                          // ha ready, hb in flight
#pragma unroll
    for (int kk = 0; kk < 2; ++kk)
#pragma unroll
      for (int mt = 0; mt < 4; ++mt) {
        acc[0][mt] = MFMA(ha[kk][mt], bh[0][kk], acc[0][mt]);
        acc[1][mt] = MFMA(ha[kk][mt], bh[1][kk], acc[1][mt]);
        acc[2][mt] = MFMA(ha[kk][mt], bh[2][kk], acc[2][mt]);
        acc[4][mt] = MFMA(ha[kk][mt], b4[kk], acc[4][mt]);
      }
    WAITV("0");                          // hb ready
#pragma unroll
    for (int kk = 0; kk < 2; ++kk)
#pragma unroll
      for (int mt = 0; mt < 4; ++mt) {
        acc[0][mt] = MFMA(hb[kk][mt], bh[0][2 + kk], acc[0][mt]);
        acc[1][mt] = MFMA(hb[kk][mt], bh[1][2 + kk], acc[1][mt]);
        acc[2][mt] = MFMA(hb[kk][mt], bh[2][2 + kk], acc[2][mt]);
        acc[4][mt] = MFMA(hb[kk][mt], b4[2 + kk], acc[4][mt]);
      }

    // ---- cross-wave reduction (8 partials -> 4) ----
    if (w >= 4) {
#pragma unroll
      for (int tt = 0; tt < 5; ++tt)
#pragma unroll
        for (int mt = 0; mt < 4; ++mt)
          *(f32x4*)&Red[w - 4][tt * 16 + lrow][mt * 16 + lkg * 4] = acc[tt][mt];
    }
    __syncthreads();
    if (w < 4) {
#pragma unroll
      for (int tt = 0; tt < 5; ++tt)
#pragma unroll
        for (int mt = 0; mt < 4; ++mt) {
          f32x4* p = (f32x4*)&Red[w][tt * 16 + lrow][mt * 16 + lkg * 4];
          *p = *p + acc[tt][mt];
        }
    }
    __syncthreads();

    // ---- epilogue: all 512 threads, 2 rows x 1 col ----
    {
      f32x2 s[5];
#pragma unroll
      for (int g = 0; g < 5; ++g) {
        f32x2 a = *(const f32x2*)&Red[0][g * 16 + ej][rpp * 2];
#pragma unroll
        for (int ww = 1; ww < 4; ++ww)
          a = a + *(const f32x2*)&Red[ww][g * 16 + ej][rpp * 2];
        s[g] = a;
      }
#pragma unroll
      for (int r = 0; r < 2; ++r) {
        float g_ = 1.f / (1.f + __expf(-(s[0][r] + bg_b)));
        float r_ = 1.f / (1.f + __expf(-(s[1][r] + br_b)));
        float z_ = 1.f / (1.f + __expf(-(s[2][r] + bz_b)));
        float n_ = tanhf(s[3][r] + bin_b + r_ * (s[4][r] + bhn_b));
        float h = g_ * ((1.f - z_) * n_ + z_ * hreg[r]);
        hreg[r] = h;
        int row = rpp * 2 + r;
        if (t == SS - 1) out[row * HH + ghcol] = h;
        else             Hst[row][ej] = (_Float16)h;
      }
    }

    // ---- publish: wave 0 only, into OUR contiguous 2KB region. Two 1KB
    // fully-coalesced store instructions (lane -> byte offset lane*16):
    // store1 rows 0..31, store2 rows 32..63. Full 64B lines, no RMW.
    if (t < SS - 1) {
      __syncthreads();                 // Hst complete
      if (w == 0) {
        const int r1 = lane >> 1, hf = (lane & 1) * 8;
        half8 hv0 = *(const half8*)&Hst[r1][hf];
        half8 hv1 = *(const half8*)&Hst[32 + r1][hf];
        _Float16* hp = Hn + ((size_t)blk * 64 * 16) + lane * 8;
        asm volatile("global_store_dwordx4 %0, %1, off sc0 sc1"
                     :: "v"(hp), "v"(hv0) : "memory");
        asm volatile("global_store_dwordx4 %0, %1, off offset:1024 sc0 sc1"
                     :: "v"(hp), "v"(hv1) : "memory");
        asm volatile("s_waitcnt vmcnt(0)" ::: "memory");  // wave 0's stores only
        __builtin_amdgcn_sched_barrier(0);
        if (lane == 0)
          __hip_atomic_store(&flags[blk], (unsigned)(t + 1), __ATOMIC_RELAXED, __HIP_MEMORY_SCOPE_AGENT);
      }
    }
  }
}

extern "C" void kernel_launch(void* const* d_in, const int* in_sizes, int n_in,
                              void* d_out, int out_size, void* d_ws, size_t ws_size,
                              hipStream_t stream) {
  const float* x   = (const float*)d_in[0];
  const float* Wg  = (const float*)d_in[1];
  const float* bg  = (const float*)d_in[2];
  const float* Wih = (const float*)d_in[3];
  const float* bih = (const float*)d_in[4];
  const float* Whh = (const float*)d_in[5];
  const float* bhh = (const float*)d_in[6];
  // d_in[7..10] (Wa, ba, Ws, bs) are mathematically dead: softmax over size-1 axis == 1
  float* out = (float*)d_out;

  char* ws = (char*)d_ws;
  _Float16* Wp    = (_Float16*)ws;                        // 15,728,640 B
  _Float16* Xh    = (_Float16*)(ws + 15728640);           // 33,554,432 B
  _Float16* Hbuf  = (_Float16*)(ws + 15728640 + 33554432);        // 262,144 B
  unsigned* flags = (unsigned*)(ws + 15728640 + 33554432 + 262144); // 256 B

  hipMemsetAsync((void*)Hbuf, 0, 262144 + 256, stream);   // h0 = 0, flags = 0
  prep_w<<<5120, 256, 0, stream>>>(Wg, Wih, Whh, Wp);
  prep_xh<<<dim3(512, 16), 256, 0, stream>>>(x, Xh);
  rnn_seq<<<64, 512, 0, stream>>>(Xh, Wp, bg, bih, bhh, out, Hbuf, flags);
}

// Round 14
// 4120.630 us; speedup vs baseline: 1.2200x; 1.2200x over previous
//
#include <hip/hip_runtime.h>

typedef _Float16 half8 __attribute__((ext_vector_type(8)));
typedef float f32x4 __attribute__((ext_vector_type(4)));
typedef float f32x2 __attribute__((ext_vector_type(2)));

#define BB 64
#define SS 512
#define DD 512
#define HH 1024
#define KK 1536
#define NBLK 64

#define MFMA(a, b, c) __builtin_amdgcn_mfma_f32_16x16x32_f16(a, b, c, 0, 0, 0)

// x-region of Wp: fragment permutation; h-region: identity on both operands
// (the shared permutation cancels inside the MFMA dot product).
__device__ __host__ __forceinline__ int kperm(int k) {
  int blk = k >> 5, r = k & 31;
  return (blk << 5) | (((r >> 2) & 3) << 3) | ((r >> 4) << 2) | (r & 3);
}

// Pack weights: Wp[p][k'] fp16, p = b*80 + tile*16 + c  (tile: 0=g,1=r,2=z,3=i_n,4=h_n)
__global__ void prep_w(const float* __restrict__ Wg, const float* __restrict__ Wih,
                       const float* __restrict__ Whh, _Float16* __restrict__ Wp) {
  int p = blockIdx.x;
  int b = p / 80, rem = p % 80, t = rem >> 4, c = rem & 15;
  int j = b * 16 + c;
  for (int pass = 0; pass < 6; ++pass) {
    int k = pass * 256 + threadIdx.x;
    float v;
    if (t == 0)      v = Wg[k * HH + j];
    else if (t == 1) v = (k < DD) ? Wih[k * 3 * HH + j]          : Whh[(k - DD) * 3 * HH + j];
    else if (t == 2) v = (k < DD) ? Wih[k * 3 * HH + HH + j]     : Whh[(k - DD) * 3 * HH + HH + j];
    else if (t == 3) v = (k < DD) ? Wih[k * 3 * HH + 2 * HH + j] : 0.f;
    else             v = (k < DD) ? 0.f : Whh[(k - DD) * 3 * HH + 2 * HH + j];
    int pos = (k < DD) ? kperm(k) : k;      // x: kperm'd, h: identity
    Wp[(size_t)p * KK + pos] = (_Float16)v;
  }
}

// Xh[t][sg][row][lkg][8]: fp16 x in fragment-ready order (sg = x k-step 0..15)
__global__ void prep_xh(const float* __restrict__ x, _Float16* __restrict__ Xh) {
  int t = blockIdx.x, sg = blockIdx.y;
  int row = threadIdx.x >> 2, lkg = threadIdx.x & 3;
  const float* xp = x + ((size_t)row * SS + t) * DD + sg * 32 + lkg * 4;
  half8 hv;
#pragma unroll
  for (int j = 0; j < 4; ++j) { hv[j] = (_Float16)xp[j]; hv[4 + j] = (_Float16)xp[16 + j]; }
  *(half8*)(Xh + ((((size_t)t * 16 + sg) * 64 + row) * 4 + lkg) * 8) = hv;
}

#define WAITV(lit) do { asm volatile("s_waitcnt vmcnt(" lit ")" ::: "memory"); \
                        __builtin_amdgcn_sched_barrier(0); } while (0)

// H exchange: Hbuf2[parity][producer p][row 0..63][16 halfs], producer-
// contiguous (r13: clean coalesced 2KB publish, no partial-line RMW).
// NEW (r14, the one change): block-rotated wave->k-slice mapping
// wk = (w + blk) & 7 de-correlates which producer regions the 64 blocks'
// wave-w read at any instant (MALL channel hotspot fix). w<->wk is a
// per-block bijection: reduction (sums all waves) and poll-union (covers
// all 64 producers) are unchanged.

__global__ __launch_bounds__(512, 2) void rnn_seq(
    const _Float16* __restrict__ Xh, const _Float16* __restrict__ Wp,
    const float* __restrict__ bg, const float* __restrict__ bih,
    const float* __restrict__ bhh, float* __restrict__ out,
    _Float16* __restrict__ Hbuf, unsigned* __restrict__ flags) {
  const int blk = blockIdx.x;
  const int tid = threadIdx.x;
  const int w = tid >> 6;              // wave 0..7
  const int lane = tid & 63;
  const int lrow = lane & 15;
  const int lkg = lane >> 4;
  const int phalf = lkg >> 1;          // producer parity within k-step
  const int chalf = (lkg & 1) * 8;     // 8-col half within producer region
  const int wk = (w + blk) & 7;        // rotated h k-slice for this wave

  __shared__ float Red[4][80][68];               // 87,040 B
  __shared__ alignas(16) _Float16 Hst[64][16];   //  2,048 B
  __shared__ alignas(16) _Float16 Xstage[64 * 512];  // 65,536 B

  const int ej = tid & 15;
  const int rpp = tid >> 4;            // 0..31
  const int ghcol = blk * 16 + ej;
  const float bg_b  = bg[ghcol];
  const float br_b  = bih[ghcol] + bhh[ghcol];
  const float bz_b  = bih[HH + ghcol] + bhh[HH + ghcol];
  const float bin_b = bih[2 * HH + ghcol];
  const float bhn_b = bhh[2 * HH + ghcol];
  float hreg[2] = {0.f, 0.f};

  // wave handles h cols [wk*128, wk*128+128) -> producers 8wk .. 8wk+7
  const int myprod = 8 * wk + (lane & 7);

  // register-resident weights (24 half8 = 96 VGPR); h-side uses wk
  half8 bx[3][2], b3[2], bh[3][4], b4[4];
#pragma unroll
  for (int tt = 0; tt < 3; ++tt)
#pragma unroll
    for (int kk = 0; kk < 2; ++kk)
      bx[tt][kk] = *(const half8*)(Wp + (size_t)(blk * 80 + tt * 16 + lrow) * KK + (w * 2 + kk) * 32 + lkg * 8);
#pragma unroll
  for (int kk = 0; kk < 2; ++kk)
    b3[kk] = *(const half8*)(Wp + (size_t)(blk * 80 + 48 + lrow) * KK + (w * 2 + kk) * 32 + lkg * 8);
#pragma unroll
  for (int tt = 0; tt < 3; ++tt)
#pragma unroll
    for (int kk = 0; kk < 4; ++kk)
      bh[tt][kk] = *(const half8*)(Wp + (size_t)(blk * 80 + tt * 16 + lrow) * KK + (16 + wk * 4 + kk) * 32 + lkg * 8);
#pragma unroll
  for (int kk = 0; kk < 4; ++kk)
    b4[kk] = *(const half8*)(Wp + (size_t)(blk * 80 + 64 + lrow) * KK + (16 + wk * 4 + kk) * 32 + lkg * 8);

  // prefetch Xstage(t=0)
#pragma unroll
  for (int kk = 0; kk < 2; ++kk)
#pragma unroll
    for (int mt = 0; mt < 4; ++mt) {
      const _Float16* gsrc = Xh + ((((size_t)0 * 16 + (w * 2 + kk)) * 64 + (mt * 16 + lrow)) * 4 + lkg) * 8;
      __builtin_amdgcn_global_load_lds(
          (const __attribute__((address_space(1))) void*)gsrc,
          (__attribute__((address_space(3))) void*)(Xstage + (w * 8 + kk * 4 + mt) * 512), 16, 0, 0);
    }
  WAITV("0");

  for (int t = 0; t < SS; ++t) {
    const _Float16* Hb = Hbuf + (size_t)(t & 1) * (BB * HH);
    _Float16* Hn = Hbuf + (size_t)((t + 1) & 1) * (BB * HH);

    f32x4 zz = {0.f, 0.f, 0.f, 0.f};
    f32x4 acc[5][4];
#pragma unroll
    for (int tt = 0; tt < 5; ++tt)
#pragma unroll
      for (int mt = 0; mt < 4; ++mt) acc[tt][mt] = zz;

    // ---- x ds_reads into registers (Xstage(t) resident via prev drain) ----
    half8 xfr[2][4];
#pragma unroll
    for (int kk = 0; kk < 2; ++kk)
#pragma unroll
      for (int mt = 0; mt < 4; ++mt)
        xfr[kk][mt] = *(const half8*)(Xstage + (w * 8 + kk * 4 + mt) * 512 + lane * 8);
    asm volatile("s_waitcnt lgkmcnt(0)" ::: "memory");   // reads retired (WAR)
    __builtin_amdgcn_sched_barrier(0);

    // ---- xpref(t+1): issued BEFORE the poll; latency hides under the wait
    {
      const int tn = (t + 1 < SS) ? t + 1 : t;
#pragma unroll
      for (int kk = 0; kk < 2; ++kk)
#pragma unroll
        for (int mt = 0; mt < 4; ++mt) {
          const _Float16* gsrc = Xh + ((((size_t)tn * 16 + (w * 2 + kk)) * 64 + (mt * 16 + lrow)) * 4 + lkg) * 8;
          __builtin_amdgcn_global_load_lds(
              (const __attribute__((address_space(1))) void*)gsrc,
              (__attribute__((address_space(3))) void*)(Xstage + (w * 8 + kk * 4 + mt) * 512), 16, 0, 0);
        }
    }

    // ---- per-wave poll: wait ONLY on this wave's 8 (rotated) producers;
    // poll-load retirement also drains xpref -> queue empty at ha issue.
    for (;;) {
      unsigned v = __hip_atomic_load(&flags[myprod], __ATOMIC_RELAXED, __HIP_MEMORY_SCOPE_AGENT);
      if (__all((int)(v >= (unsigned)t))) break;
      __builtin_amdgcn_s_sleep(1);
    }
    __builtin_amdgcn_sched_barrier(0);

    // ---- issue both h batches (producer-contiguous addressing, rotated);
    // x-MFMA below hides their latency ----
    half8 ha[2][4], hb[2][4];
#pragma unroll
    for (int kk = 0; kk < 2; ++kk)
#pragma unroll
      for (int mt = 0; mt < 4; ++mt) {
        const int p = (wk * 4 + kk) * 2 + phalf;
        const _Float16* hp = Hb + ((size_t)(p * 64 + mt * 16 + lrow) * 16 + chalf);
        asm volatile("global_load_dwordx4 %0, %1, off sc0 sc1"
                     : "=&v"(ha[kk][mt]) : "v"(hp) : "memory");
      }
#pragma unroll
    for (int kk = 0; kk < 2; ++kk)
#pragma unroll
      for (int mt = 0; mt < 4; ++mt) {
        const int p = (wk * 4 + 2 + kk) * 2 + phalf;
        const _Float16* hp = Hb + ((size_t)(p * 64 + mt * 16 + lrow) * 16 + chalf);
        asm volatile("global_load_dwordx4 %0, %1, off sc0 sc1"
                     : "=&v"(hb[kk][mt]) : "v"(hp) : "memory");
      }

    // ---- x-MFMA from registers (overlaps h-load round trip) ----
#pragma unroll
    for (int kk = 0; kk < 2; ++kk)
#pragma unroll
      for (int mt = 0; mt < 4; ++mt) {
        acc[0][mt] = MFMA(xfr[kk][mt], bx[0][kk], acc[0][mt]);
        acc[1][mt] = MFMA(xfr[kk][mt], bx[1][kk], acc[1][mt]);
        acc[2][mt] = MFMA(xfr[kk][mt], bx[2][kk], acc[2][mt]);
        acc[3][mt] = MFMA(xfr[kk][mt], b3[kk], acc[3][mt]);
      }

    // ---- h-MFMA: counted waits (queue exactly [ha:8][hb:8] here) ----
    WAITV("8");                          // ha ready, hb in flight
#pragma unroll
    for (int kk = 0; kk < 2; ++kk)
#pragma unroll
      for (int mt = 0; mt < 4; ++mt) {
        acc[0][mt] = MFMA(ha[kk][mt], bh[0][kk], acc[0][mt]);
        acc[1][mt] = MFMA(ha[kk][mt], bh[1][kk], acc[1][mt]);
        acc[2][mt] = MFMA(ha[kk][mt], bh[2][kk], acc[2][mt]);
        acc[4][mt] = MFMA(ha[kk][mt], b4[kk], acc[4][mt]);
      }
    WAITV("0");                          // hb ready
#pragma unroll
    for (int kk = 0; kk < 2; ++kk)
#pragma unroll
      for (int mt = 0; mt < 4; ++mt) {
        acc[0][mt] = MFMA(hb[kk][mt], bh[0][2 + kk], acc[0][mt]);
        acc[1][mt] = MFMA(hb[kk][mt], bh[1][2 + kk], acc[1][mt]);
        acc[2][mt] = MFMA(hb[kk][mt], bh[2][2 + kk], acc[2][mt]);
        acc[4][mt] = MFMA(hb[kk][mt], b4[2 + kk], acc[4][mt]);
      }

    // ---- cross-wave reduction (8 partials -> 4): sums ALL waves, so the
    // w<->wk rotation needs no changes here ----
    if (w >= 4) {
#pragma unroll
      for (int tt = 0; tt < 5; ++tt)
#pragma unroll
        for (int mt = 0; mt < 4; ++mt)
          *(f32x4*)&Red[w - 4][tt * 16 + lrow][mt * 16 + lkg * 4] = acc[tt][mt];
    }
    __syncthreads();
    if (w < 4) {
#pragma unroll
      for (int tt = 0; tt < 5; ++tt)
#pragma unroll
        for (int mt = 0; mt < 4; ++mt) {
          f32x4* p = (f32x4*)&Red[w][tt * 16 + lrow][mt * 16 + lkg * 4];
          *p = *p + acc[tt][mt];
        }
    }
    __syncthreads();

    // ---- epilogue: all 512 threads, 2 rows x 1 col ----
    {
      f32x2 s[5];
#pragma unroll
      for (int g = 0; g < 5; ++g) {
        f32x2 a = *(const f32x2*)&Red[0][g * 16 + ej][rpp * 2];
#pragma unroll
        for (int ww = 1; ww < 4; ++ww)
          a = a + *(const f32x2*)&Red[ww][g * 16 + ej][rpp * 2];
        s[g] = a;
      }
#pragma unroll
      for (int r = 0; r < 2; ++r) {
        float g_ = 1.f / (1.f + __expf(-(s[0][r] + bg_b)));
        float r_ = 1.f / (1.f + __expf(-(s[1][r] + br_b)));
        float z_ = 1.f / (1.f + __expf(-(s[2][r] + bz_b)));
        float n_ = tanhf(s[3][r] + bin_b + r_ * (s[4][r] + bhn_b));
        float h = g_ * ((1.f - z_) * n_ + z_ * hreg[r]);
        hreg[r] = h;
        int row = rpp * 2 + r;
        if (t == SS - 1) out[row * HH + ghcol] = h;
        else             Hst[row][ej] = (_Float16)h;
      }
    }

    // ---- publish: wave 0 only, into OUR contiguous 2KB region. Two 1KB
    // fully-coalesced store instructions; full 64B lines, no RMW.
    if (t < SS - 1) {
      __syncthreads();                 // Hst complete
      if (w == 0) {
        const int r1 = lane >> 1, hf = (lane & 1) * 8;
        half8 hv0 = *(const half8*)&Hst[r1][hf];
        half8 hv1 = *(const half8*)&Hst[32 + r1][hf];
        _Float16* hp = Hn + ((size_t)blk * 64 * 16) + lane * 8;
        asm volatile("global_store_dwordx4 %0, %1, off sc0 sc1"
                     :: "v"(hp), "v"(hv0) : "memory");
        asm volatile("global_store_dwordx4 %0, %1, off offset:1024 sc0 sc1"
                     :: "v"(hp), "v"(hv1) : "memory");
        asm volatile("s_waitcnt vmcnt(0)" ::: "memory");  // wave 0's stores only
        __builtin_amdgcn_sched_barrier(0);
        if (lane == 0)
          __hip_atomic_store(&flags[blk], (unsigned)(t + 1), __ATOMIC_RELAXED, __HIP_MEMORY_SCOPE_AGENT);
      }
    }
  }
}

extern "C" void kernel_launch(void* const* d_in, const int* in_sizes, int n_in,
                              void* d_out, int out_size, void* d_ws, size_t ws_size,
                              hipStream_t stream) {
  const float* x   = (const float*)d_in[0];
  const float* Wg  = (const float*)d_in[1];
  const float* bg  = (const float*)d_in[2];
  const float* Wih = (const float*)d_in[3];
  const float* bih = (const float*)d_in[4];
  const float* Whh = (const float*)d_in[5];
  const float* bhh = (const float*)d_in[6];
  // d_in[7..10] (Wa, ba, Ws, bs) are mathematically dead: softmax over size-1 axis == 1
  float* out = (float*)d_out;

  char* ws = (char*)d_ws;
  _Float16* Wp    = (_Float16*)ws;                        // 15,728,640 B
  _Float16* Xh    = (_Float16*)(ws + 15728640);           // 33,554,432 B
  _Float16* Hbuf  = (_Float16*)(ws + 15728640 + 33554432);        // 262,144 B
  unsigned* flags = (unsigned*)(ws + 15728640 + 33554432 + 262144); // 256 B

  hipMemsetAsync((void*)Hbuf, 0, 262144 + 256, stream);   // h0 = 0, flags = 0
  prep_w<<<5120, 256, 0, stream>>>(Wg, Wih, Whh, Wp);
  prep_xh<<<dim3(512, 16), 256, 0, stream>>>(x, Xh);
  rnn_seq<<<64, 512, 0, stream>>>(Xh, Wp, bg, bih, bhh, out, Hbuf, flags);
}

// Round 15
// 2921.339 us; speedup vs baseline: 1.7208x; 1.4105x over previous
//
#include <hip/hip_runtime.h>

typedef _Float16 half8 __attribute__((ext_vector_type(8)));
typedef float f32x4 __attribute__((ext_vector_type(4)));

#define BB 64
#define SS 512
#define DD 512
#define HH 1024
#define KK 1536
#define GG 4               // independent batch-row groups (rings)
#define RR 16              // rows per group

#define MFMA(a, b, c) __builtin_amdgcn_mfma_f32_16x16x32_f16(a, b, c, 0, 0, 0)

// x-region of Wp: fragment permutation; h-region: identity on both operands
// (the shared permutation cancels inside the MFMA dot product).
__device__ __host__ __forceinline__ int kperm(int k) {
  int blk = k >> 5, r = k & 31;
  return (blk << 5) | (((r >> 2) & 3) << 3) | ((r >> 4) << 2) | (r & 3);
}

// Pack weights: Wp[p][k'] fp16, p = b*80 + tile*16 + c  (tile: 0=g,1=r,2=z,3=i_n,4=h_n)
// Weights are batch-row independent -> shared by all 4 groups unchanged.
__global__ void prep_w(const float* __restrict__ Wg, const float* __restrict__ Wih,
                       const float* __restrict__ Whh, _Float16* __restrict__ Wp) {
  int p = blockIdx.x;
  int b = p / 80, rem = p % 80, t = rem >> 4, c = rem & 15;
  int j = b * 16 + c;
  for (int pass = 0; pass < 6; ++pass) {
    int k = pass * 256 + threadIdx.x;
    float v;
    if (t == 0)      v = Wg[k * HH + j];
    else if (t == 1) v = (k < DD) ? Wih[k * 3 * HH + j]          : Whh[(k - DD) * 3 * HH + j];
    else if (t == 2) v = (k < DD) ? Wih[k * 3 * HH + HH + j]     : Whh[(k - DD) * 3 * HH + HH + j];
    else if (t == 3) v = (k < DD) ? Wih[k * 3 * HH + 2 * HH + j] : 0.f;
    else             v = (k < DD) ? 0.f : Whh[(k - DD) * 3 * HH + 2 * HH + j];
    int pos = (k < DD) ? kperm(k) : k;      // x: kperm'd, h: identity
    Wp[(size_t)p * KK + pos] = (_Float16)v;
  }
}

// Xh[t][sg][row 0..63][lkg][8]: fp16 x in fragment-ready order (unchanged)
__global__ void prep_xh(const float* __restrict__ x, _Float16* __restrict__ Xh) {
  int t = blockIdx.x, sg = blockIdx.y;
  int row = threadIdx.x >> 2, lkg = threadIdx.x & 3;
  const float* xp = x + ((size_t)row * SS + t) * DD + sg * 32 + lkg * 4;
  half8 hv;
#pragma unroll
  for (int j = 0; j < 4; ++j) { hv[j] = (_Float16)xp[j]; hv[4 + j] = (_Float16)xp[16 + j]; }
  *(half8*)(Xh + ((((size_t)t * 16 + sg) * 64 + row) * 4 + lkg) * 8) = hv;
}

#define WAITV(lit) do { asm volatile("s_waitcnt vmcnt(" lit ")" ::: "memory"); \
                        __builtin_amdgcn_sched_barrier(0); } while (0)

// Grid = 256 blocks = GG groups x 64 column-blocks. Batch rows are fully
// independent, so the 4 groups are 4 decoupled rings; each ring runs the
// r14 protocol verbatim (producer-contiguous Hbuf region, wave0-publish,
// rotated fan-in-8 polls, counted vmcnt waits) on 16 rows instead of 64.
// Per-group Hbuf: [parity][producer cb][row 0..15][16 halfs] (512B/publish).

__global__ __launch_bounds__(512, 2) void rnn_seq(
    const _Float16* __restrict__ Xh, const _Float16* __restrict__ Wp,
    const float* __restrict__ bg, const float* __restrict__ bih,
    const float* __restrict__ bhh, float* __restrict__ out,
    _Float16* __restrict__ Hbuf, unsigned* __restrict__ flags) {
  const int blk = blockIdx.x;          // 0..255
  const int g = blk >> 6;              // batch-row group 0..3 (rows g*16..+16)
  const int cb = blk & 63;             // column block 0..63
  const int tid = threadIdx.x;
  const int w = tid >> 6;              // wave 0..7 (K-split)
  const int lane = tid & 63;
  const int lrow = lane & 15;
  const int lkg = lane >> 4;
  const int phalf = lkg >> 1;          // producer parity within k-step
  const int chalf = (lkg & 1) * 8;     // 8-col half within producer region
  const int wk = (w + cb) & 7;         // rotated h k-slice (r14 hotspot fix)

  __shared__ float Red[4][80][18];               // 23,040 B
  __shared__ alignas(16) _Float16 Hst[RR][16];   //    512 B
  __shared__ alignas(16) _Float16 Xstage[16 * 512];  // 16,384 B

  const int ej = tid & 15;
  const int rr = (tid >> 4) & 15;      // epilogue row (tid<256: 1 row x 1 col)
  const int ghcol = cb * 16 + ej;
  const float bg_b  = bg[ghcol];
  const float br_b  = bih[ghcol] + bhh[ghcol];
  const float bz_b  = bih[HH + ghcol] + bhh[HH + ghcol];
  const float bin_b = bih[2 * HH + ghcol];
  const float bhn_b = bhh[2 * HH + ghcol];
  float hreg = 0.f;

  // wave handles h cols [wk*128, +128) -> producers 8wk..8wk+7 of THIS group
  const int myprod = g * 64 + 8 * wk + (lane & 7);

  // per-group H exchange base: 2 parities x 64 producers x RR x 16 halfs
  _Float16* HbufG = Hbuf + (size_t)g * (2 * 64 * RR * 16);

  // register-resident weights (24 half8 = 96 VGPR); h-side uses wk
  half8 bx[3][2], b3[2], bh[3][4], b4[4];
#pragma unroll
  for (int tt = 0; tt < 3; ++tt)
#pragma unroll
    for (int kk = 0; kk < 2; ++kk)
      bx[tt][kk] = *(const half8*)(Wp + (size_t)(cb * 80 + tt * 16 + lrow) * KK + (w * 2 + kk) * 32 + lkg * 8);
#pragma unroll
  for (int kk = 0; kk < 2; ++kk)
    b3[kk] = *(const half8*)(Wp + (size_t)(cb * 80 + 48 + lrow) * KK + (w * 2 + kk) * 32 + lkg * 8);
#pragma unroll
  for (int tt = 0; tt < 3; ++tt)
#pragma unroll
    for (int kk = 0; kk < 4; ++kk)
      bh[tt][kk] = *(const half8*)(Wp + (size_t)(cb * 80 + tt * 16 + lrow) * KK + (16 + wk * 4 + kk) * 32 + lkg * 8);
#pragma unroll
  for (int kk = 0; kk < 4; ++kk)
    b4[kk] = *(const half8*)(Wp + (size_t)(cb * 80 + 64 + lrow) * KK + (16 + wk * 4 + kk) * 32 + lkg * 8);

  // prefetch Xstage(t=0): per wave 2 chunks of 1KB (16 rows x 64B)
#pragma unroll
  for (int kk = 0; kk < 2; ++kk) {
    const _Float16* gsrc = Xh + ((((size_t)0 * 16 + (w * 2 + kk)) * 64 + (g * RR + lrow)) * 4 + lkg) * 8;
    __builtin_amdgcn_global_load_lds(
        (const __attribute__((address_space(1))) void*)gsrc,
        (__attribute__((address_space(3))) void*)(Xstage + (w * 2 + kk) * 512), 16, 0, 0);
  }
  WAITV("0");

  for (int t = 0; t < SS; ++t) {
    const _Float16* Hb = HbufG + (size_t)(t & 1) * (64 * RR * 16);
    _Float16* Hn = HbufG + (size_t)((t + 1) & 1) * (64 * RR * 16);

    f32x4 zz = {0.f, 0.f, 0.f, 0.f};
    f32x4 acc[5];
#pragma unroll
    for (int tt = 0; tt < 5; ++tt) acc[tt] = zz;

    // ---- x ds_reads into registers (Xstage(t) resident via prev drain) ----
    half8 xfr[2];
#pragma unroll
    for (int kk = 0; kk < 2; ++kk)
      xfr[kk] = *(const half8*)(Xstage + (w * 2 + kk) * 512 + lane * 8);
    asm volatile("s_waitcnt lgkmcnt(0)" ::: "memory");   // reads retired (WAR)
    __builtin_amdgcn_sched_barrier(0);

    // ---- xpref(t+1): issued BEFORE the poll; latency hides under the wait
    {
      const int tn = (t + 1 < SS) ? t + 1 : t;
#pragma unroll
      for (int kk = 0; kk < 2; ++kk) {
        const _Float16* gsrc = Xh + ((((size_t)tn * 16 + (w * 2 + kk)) * 64 + (g * RR + lrow)) * 4 + lkg) * 8;
        __builtin_amdgcn_global_load_lds(
            (const __attribute__((address_space(1))) void*)gsrc,
            (__attribute__((address_space(3))) void*)(Xstage + (w * 2 + kk) * 512), 16, 0, 0);
      }
    }

    // ---- per-wave poll: this wave's 8 (rotated) producers of OUR group;
    // poll-load retirement also drains xpref -> queue empty at ha issue.
    for (;;) {
      unsigned v = __hip_atomic_load(&flags[myprod], __ATOMIC_RELAXED, __HIP_MEMORY_SCOPE_AGENT);
      if (__all((int)(v >= (unsigned)t))) break;
      __builtin_amdgcn_s_sleep(1);
    }
    __builtin_amdgcn_sched_barrier(0);

    // ---- issue both h batches (producer-contiguous, rotated) ----
    half8 ha[2], hbv[2];
#pragma unroll
    for (int kk = 0; kk < 2; ++kk) {
      const int p = (wk * 4 + kk) * 2 + phalf;
      const _Float16* hp = Hb + ((size_t)(p * RR + lrow) * 16 + chalf);
      asm volatile("global_load_dwordx4 %0, %1, off sc0 sc1"
                   : "=&v"(ha[kk]) : "v"(hp) : "memory");
    }
#pragma unroll
    for (int kk = 0; kk < 2; ++kk) {
      const int p = (wk * 4 + 2 + kk) * 2 + phalf;
      const _Float16* hp = Hb + ((size_t)(p * RR + lrow) * 16 + chalf);
      asm volatile("global_load_dwordx4 %0, %1, off sc0 sc1"
                   : "=&v"(hbv[kk]) : "v"(hp) : "memory");
    }

    // ---- x-MFMA from registers (overlaps h-load round trip) ----
#pragma unroll
    for (int kk = 0; kk < 2; ++kk) {
      acc[0] = MFMA(xfr[kk], bx[0][kk], acc[0]);
      acc[1] = MFMA(xfr[kk], bx[1][kk], acc[1]);
      acc[2] = MFMA(xfr[kk], bx[2][kk], acc[2]);
      acc[3] = MFMA(xfr[kk], b3[kk], acc[3]);
    }

    // ---- h-MFMA: counted waits (queue exactly [ha:2][hbv:2] here) ----
    WAITV("2");                          // ha ready, hbv in flight
#pragma unroll
    for (int kk = 0; kk < 2; ++kk) {
      acc[0] = MFMA(ha[kk], bh[0][kk], acc[0]);
      acc[1] = MFMA(ha[kk], bh[1][kk], acc[1]);
      acc[2] = MFMA(ha[kk], bh[2][kk], acc[2]);
      acc[4] = MFMA(ha[kk], b4[kk], acc[4]);
    }
    WAITV("0");                          // hbv ready
#pragma unroll
    for (int kk = 0; kk < 2; ++kk) {
      acc[0] = MFMA(hbv[kk], bh[0][2 + kk], acc[0]);
      acc[1] = MFMA(hbv[kk], bh[1][2 + kk], acc[1]);
      acc[2] = MFMA(hbv[kk], bh[2][2 + kk], acc[2]);
      acc[4] = MFMA(hbv[kk], b4[2 + kk], acc[4]);
    }

    // ---- cross-wave reduction (8 partials -> 4 slabs); rotation needs no
    // changes here (sums all waves). C-layout: col=lane&15, row=lkg*4+r.
    if (w >= 4) {
#pragma unroll
      for (int tt = 0; tt < 5; ++tt)
        *(f32x4*)&Red[w - 4][tt * 16 + lrow][lkg * 4] = acc[tt];
    }
    __syncthreads();
    if (w < 4) {
#pragma unroll
      for (int tt = 0; tt < 5; ++tt) {
        f32x4* p = (f32x4*)&Red[w][tt * 16 + lrow][lkg * 4];
        *p = *p + acc[tt];
      }
    }
    __syncthreads();

    // ---- epilogue: 256 threads, 1 row x 1 col each ----
    if (tid < 256) {
      float s[5];
#pragma unroll
      for (int g5 = 0; g5 < 5; ++g5)
        s[g5] = Red[0][g5 * 16 + ej][rr] + Red[1][g5 * 16 + ej][rr]
              + Red[2][g5 * 16 + ej][rr] + Red[3][g5 * 16 + ej][rr];
      float g_ = 1.f / (1.f + __expf(-(s[0] + bg_b)));
      float r_ = 1.f / (1.f + __expf(-(s[1] + br_b)));
      float z_ = 1.f / (1.f + __expf(-(s[2] + bz_b)));
      float n_ = tanhf(s[3] + bin_b + r_ * (s[4] + bhn_b));
      float h = g_ * ((1.f - z_) * n_ + z_ * hreg);
      hreg = h;
      if (t == SS - 1) out[(size_t)(g * RR + rr) * HH + ghcol] = h;
      else             Hst[rr][ej] = (_Float16)h;
    }

    // ---- publish: wave 0 only, into OUR contiguous 512B region (8 full
    // 64B lines, one coalesced store on lanes 0-31). Last barrier of the
    // step; waves 1-7 race ahead (hazard argument identical to r12-r14).
    if (t < SS - 1) {
      __syncthreads();                 // Hst complete
      if (w == 0) {
        if (lane < 32) {
          const int r1 = lane >> 1, hf = (lane & 1) * 8;
          half8 hv = *(const half8*)&Hst[r1][hf];
          _Float16* hp = Hn + ((size_t)cb * RR * 16) + lane * 8;
          asm volatile("global_store_dwordx4 %0, %1, off sc0 sc1"
                       :: "v"(hp), "v"(hv) : "memory");
        }
        asm volatile("s_waitcnt vmcnt(0)" ::: "memory");  // wave 0's stores only
        __builtin_amdgcn_sched_barrier(0);
        if (lane == 0)
          __hip_atomic_store(&flags[g * 64 + cb], (unsigned)(t + 1),
                             __ATOMIC_RELAXED, __HIP_MEMORY_SCOPE_AGENT);
      }
    }
  }
}

extern "C" void kernel_launch(void* const* d_in, const int* in_sizes, int n_in,
                              void* d_out, int out_size, void* d_ws, size_t ws_size,
                              hipStream_t stream) {
  const float* x   = (const float*)d_in[0];
  const float* Wg  = (const float*)d_in[1];
  const float* bg  = (const float*)d_in[2];
  const float* Wih = (const float*)d_in[3];
  const float* bih = (const float*)d_in[4];
  const float* Whh = (const float*)d_in[5];
  const float* bhh = (const float*)d_in[6];
  // d_in[7..10] (Wa, ba, Ws, bs) are mathematically dead: softmax over size-1 axis == 1
  float* out = (float*)d_out;

  char* ws = (char*)d_ws;
  _Float16* Wp    = (_Float16*)ws;                        // 15,728,640 B
  _Float16* Xh    = (_Float16*)(ws + 15728640);           // 33,554,432 B
  _Float16* Hbuf  = (_Float16*)(ws + 15728640 + 33554432);        // 4*2*64*16*16*2 = 262,144 B
  unsigned* flags = (unsigned*)(ws + 15728640 + 33554432 + 262144); // 4*64*4 = 1,024 B

  hipMemsetAsync((void*)Hbuf, 0, 262144 + 1024, stream);  // h0 = 0, flags = 0
  prep_w<<<5120, 256, 0, stream>>>(Wg, Wih, Whh, Wp);
  prep_xh<<<dim3(512, 16), 256, 0, stream>>>(x, Xh);
  rnn_seq<<<256, 512, 0, stream>>>(Xh, Wp, bg, bih, bhh, out, Hbuf, flags);
}

// Round 16
// 2197.006 us; speedup vs baseline: 2.2881x; 1.3297x over previous
//
#include <hip/hip_runtime.h>

typedef _Float16 half8 __attribute__((ext_vector_type(8)));
typedef float f32x4 __attribute__((ext_vector_type(4)));
typedef unsigned uint4v __attribute__((ext_vector_type(4)));

#define BB 64
#define SS 512
#define DD 512
#define HH 1024
#define KK 1536
#define GG 4               // independent batch-row groups (rings)
#define RR 16              // rows per group
#define PKST 48            // 16B packets per producer region (3 per row)

#define MFMA(a, b, c) __builtin_amdgcn_mfma_f32_16x16x32_f16(a, b, c, 0, 0, 0)

// x-region of Wp: fragment permutation; h-region: identity on both operands
// (the shared permutation cancels inside the MFMA dot product).
__device__ __host__ __forceinline__ int kperm(int k) {
  int blk = k >> 5, r = k & 31;
  return (blk << 5) | (((r >> 2) & 3) << 3) | ((r >> 4) << 2) | (r & 3);
}

// Pack weights: Wp[p][k'] fp16, p = b*80 + tile*16 + c  (tile: 0=g,1=r,2=z,3=i_n,4=h_n)
__global__ void prep_w(const float* __restrict__ Wg, const float* __restrict__ Wih,
                       const float* __restrict__ Whh, _Float16* __restrict__ Wp) {
  int p = blockIdx.x;
  int b = p / 80, rem = p % 80, t = rem >> 4, c = rem & 15;
  int j = b * 16 + c;
  for (int pass = 0; pass < 6; ++pass) {
    int k = pass * 256 + threadIdx.x;
    float v;
    if (t == 0)      v = Wg[k * HH + j];
    else if (t == 1) v = (k < DD) ? Wih[k * 3 * HH + j]          : Whh[(k - DD) * 3 * HH + j];
    else if (t == 2) v = (k < DD) ? Wih[k * 3 * HH + HH + j]     : Whh[(k - DD) * 3 * HH + HH + j];
    else if (t == 3) v = (k < DD) ? Wih[k * 3 * HH + 2 * HH + j] : 0.f;
    else             v = (k < DD) ? 0.f : Whh[(k - DD) * 3 * HH + 2 * HH + j];
    int pos = (k < DD) ? kperm(k) : k;      // x: kperm'd, h: identity
    Wp[(size_t)p * KK + pos] = (_Float16)v;
  }
}

// Xh[t][sg][row 0..63][lkg][8]: fp16 x in fragment-ready order
__global__ void prep_xh(const float* __restrict__ x, _Float16* __restrict__ Xh) {
  int t = blockIdx.x, sg = blockIdx.y;
  int row = threadIdx.x >> 2, lkg = threadIdx.x & 3;
  const float* xp = x + ((size_t)row * SS + t) * DD + sg * 32 + lkg * 4;
  half8 hv;
#pragma unroll
  for (int j = 0; j < 4; ++j) { hv[j] = (_Float16)xp[j]; hv[4 + j] = (_Float16)xp[16 + j]; }
  *(half8*)(Xh + ((((size_t)t * 16 + sg) * 64 + row) * 4 + lkg) * 8) = hv;
}

#define WAITV(lit) do { asm volatile("s_waitcnt vmcnt(" lit ")" ::: "memory"); \
                        __builtin_amdgcn_sched_barrier(0); } while (0)

// ---- tagged-packet H exchange (replaces flags + drain + poll) -------------
// Region (group g, parity b, producer cb) = PKST x 16B packets at
// Pk + ((g*2+b)*64 + cb)*PKST. Per row r: pkt 3r={cols0-5,tag},
// 3r+1={cols6-11,tag}, 3r+2={cols12-15,0,tag}; tag = step whose h this is.
// Producer publish = 48 consecutive 16B stores (768B, 12 full lines,
// coalesced) fire-and-forget -- no drain, no flag. Consumer's load IS the
// poll: per-packet tag check; 16B stores are single-copy atomic (r6-r8).
// Consumer fragment (8 cols from col0=(lkg&1)*8 of producer p): packets
// {3*lrow+(lkg&1), +1}; dword select even={P0.xyz,P1.x} odd={P0.yz,P1.xy}.

__device__ __forceinline__ void issue_pk2(const uint4v* ap, uint4v& P0, uint4v& P1) {
  asm volatile("global_load_dwordx4 %0, %2, off sc0 sc1\n\t"
               "global_load_dwordx4 %1, %2, off offset:16 sc0 sc1"
               : "=&v"(P0), "=&v"(P1) : "v"(ap) : "memory");
}

__device__ __forceinline__ int tags_ok2(const uint4v& P0, const uint4v& P1, unsigned want) {
  return __all((int)(((P0[3] ^ want) | (P1[3] ^ want)) == 0));
}

// Retry (rare): reissue just this batch; vmcnt(0) makes later counted waits
// no-ops, which stays safe (regs already written; staleness re-checked).
#define RETRY2(P0a, P1a, pidx) do { \
    if (!tags_ok2(P0a, P1a, want)) { \
      const uint4v* ap_ = Rg + (size_t)(pidx) * PKST + pk_off; \
      do { issue_pk2(ap_, P0a, P1a); WAITV("0"); } \
      while (!tags_ok2(P0a, P1a, want)); } } while (0)

__global__ __launch_bounds__(512, 2) void rnn_seq(
    const _Float16* __restrict__ Xh, const _Float16* __restrict__ Wp,
    const float* __restrict__ bg, const float* __restrict__ bih,
    const float* __restrict__ bhh, float* __restrict__ out,
    uint4v* __restrict__ Pk) {
  const int blk = blockIdx.x;          // 0..255
  const int g = blk >> 6;              // batch-row group 0..3 (rows g*16..+16)
  const int cb = blk & 63;             // column block 0..63
  const int tid = threadIdx.x;
  const int w = tid >> 6;              // wave 0..7 (K-split)
  const int lane = tid & 63;
  const int lrow = lane & 15;
  const int lkg = lane >> 4;
  const int phalf = lkg >> 1;          // which producer of the k-step pair
  const int odd = lkg & 1;             // which 8-col half -> packet pair
  const int wk = (w + cb) & 7;         // rotated h k-slice (r14 hotspot fix)
  const int pk_off = 3 * lrow + odd;   // first packet index within region

  __shared__ float Red[4][80][18];               // 23,040 B
  __shared__ alignas(16) _Float16 Hst[RR][16];   //    512 B
  __shared__ alignas(16) _Float16 Xstage[16 * 512];  // 16,384 B

  const int ej = tid & 15;
  const int rr = (tid >> 4) & 15;
  const int ghcol = cb * 16 + ej;
  const float bg_b  = bg[ghcol];
  const float br_b  = bih[ghcol] + bhh[ghcol];
  const float bz_b  = bih[HH + ghcol] + bhh[HH + ghcol];
  const float bin_b = bih[2 * HH + ghcol];
  const float bhn_b = bhh[2 * HH + ghcol];
  float hreg = 0.f;

  // producer block index for batch kk: p = (wk*4+kk)*2 + phalf
  const int pbase = wk * 8 + phalf;    // p = pbase + kk*2

  // register-resident weights (24 half8 = 96 VGPR); h-side uses wk
  half8 bx[3][2], b3[2], bh[3][4], b4[4];
#pragma unroll
  for (int tt = 0; tt < 3; ++tt)
#pragma unroll
    for (int kk = 0; kk < 2; ++kk)
      bx[tt][kk] = *(const half8*)(Wp + (size_t)(cb * 80 + tt * 16 + lrow) * KK + (w * 2 + kk) * 32 + lkg * 8);
#pragma unroll
  for (int kk = 0; kk < 2; ++kk)
    b3[kk] = *(const half8*)(Wp + (size_t)(cb * 80 + 48 + lrow) * KK + (w * 2 + kk) * 32 + lkg * 8);
#pragma unroll
  for (int tt = 0; tt < 3; ++tt)
#pragma unroll
    for (int kk = 0; kk < 4; ++kk)
      bh[tt][kk] = *(const half8*)(Wp + (size_t)(cb * 80 + tt * 16 + lrow) * KK + (16 + wk * 4 + kk) * 32 + lkg * 8);
#pragma unroll
  for (int kk = 0; kk < 4; ++kk)
    b4[kk] = *(const half8*)(Wp + (size_t)(cb * 80 + 64 + lrow) * KK + (16 + wk * 4 + kk) * 32 + lkg * 8);

  // prefetch Xstage(t=0)
#pragma unroll
  for (int kk = 0; kk < 2; ++kk) {
    const _Float16* gsrc = Xh + ((((size_t)0 * 16 + (w * 2 + kk)) * 64 + (g * RR + lrow)) * 4 + lkg) * 8;
    __builtin_amdgcn_global_load_lds(
        (const __attribute__((address_space(1))) void*)gsrc,
        (__attribute__((address_space(3))) void*)(Xstage + (w * 2 + kk) * 512), 16, 0, 0);
  }
  WAITV("0");

  for (int t = 0; t < SS; ++t) {
    const uint4v* Rg = Pk + (size_t)((g * 2 + (t & 1)) * 64) * PKST;
    uint4v* Rn = Pk + (size_t)((g * 2 + ((t + 1) & 1)) * 64) * PKST;
    const unsigned want = (unsigned)t;

    f32x4 zz = {0.f, 0.f, 0.f, 0.f};
    f32x4 acc[5];
#pragma unroll
    for (int tt = 0; tt < 5; ++tt) acc[tt] = zz;

    // ---- x ds_reads into registers ----
    half8 xfr[2];
#pragma unroll
    for (int kk = 0; kk < 2; ++kk)
      xfr[kk] = *(const half8*)(Xstage + (w * 2 + kk) * 512 + lane * 8);
    asm volatile("s_waitcnt lgkmcnt(0)" ::: "memory");   // reads retired (WAR)
    __builtin_amdgcn_sched_barrier(0);

    // ---- xpref(t+1) FIRST: retires by kk0's counted wait, so next step's
    // ds_reads need no extra wait; wave0's publish store also retires there.
    {
      const int tn = (t + 1 < SS) ? t + 1 : t;
#pragma unroll
      for (int kk = 0; kk < 2; ++kk) {
        const _Float16* gsrc = Xh + ((((size_t)tn * 16 + (w * 2 + kk)) * 64 + (g * RR + lrow)) * 4 + lkg) * 8;
        __builtin_amdgcn_global_load_lds(
            (const __attribute__((address_space(1))) void*)gsrc,
            (__attribute__((address_space(3))) void*)(Xstage + (w * 2 + kk) * 512), 16, 0, 0);
      }
    }

    // ---- issue all 4 packet batches; RTs overlap x-MFMA. Queue/wave:
    // [pub:1 (w0,t>0)][xpref:2][A:2][B:2][C:2][D:2]
    uint4v A0, A1, B0, B1, C0, C1, D0, D1;
    issue_pk2(Rg + (size_t)(pbase + 0) * PKST + pk_off, A0, A1);
    issue_pk2(Rg + (size_t)(pbase + 2) * PKST + pk_off, B0, B1);
    issue_pk2(Rg + (size_t)(pbase + 4) * PKST + pk_off, C0, C1);
    issue_pk2(Rg + (size_t)(pbase + 6) * PKST + pk_off, D0, D1);

    // ---- x-MFMA from registers (overlaps packet round trips) ----
#pragma unroll
    for (int kk = 0; kk < 2; ++kk) {
      acc[0] = MFMA(xfr[kk], bx[0][kk], acc[0]);
      acc[1] = MFMA(xfr[kk], bx[1][kk], acc[1]);
      acc[2] = MFMA(xfr[kk], bx[2][kk], acc[2]);
      acc[3] = MFMA(xfr[kk], b3[kk], acc[3]);
    }

    // ---- h-MFMA: counted waits 6/4/2/0 (= loads issued after target batch;
    // safe upper bounds even after a retry's vmcnt(0)) ----
#pragma unroll
    for (int kk = 0; kk < 4; ++kk) {
      uint4v P0, P1;
      if (kk == 0)      { WAITV("6"); RETRY2(A0, A1, pbase + 0); P0 = A0; P1 = A1; }
      else if (kk == 1) { WAITV("4"); RETRY2(B0, B1, pbase + 2); P0 = B0; P1 = B1; }
      else if (kk == 2) { WAITV("2"); RETRY2(C0, C1, pbase + 4); P0 = C0; P1 = C1; }
      else              { WAITV("0"); RETRY2(D0, D1, pbase + 6); P0 = D0; P1 = D1; }
      uint4v fv;
      fv[0] = odd ? P0[1] : P0[0];
      fv[1] = odd ? P0[2] : P0[1];
      fv[2] = odd ? P1[0] : P0[2];
      fv[3] = odd ? P1[1] : P1[0];
      half8 af = __builtin_bit_cast(half8, fv);
      acc[0] = MFMA(af, bh[0][kk], acc[0]);
      acc[1] = MFMA(af, bh[1][kk], acc[1]);
      acc[2] = MFMA(af, bh[2][kk], acc[2]);
      acc[4] = MFMA(af, b4[kk], acc[4]);
    }

    // ---- cross-wave reduction (8 partials -> 4 slabs) ----
    if (w >= 4) {
#pragma unroll
      for (int tt = 0; tt < 5; ++tt)
        *(f32x4*)&Red[w - 4][tt * 16 + lrow][lkg * 4] = acc[tt];
    }
    __syncthreads();
    if (w < 4) {
#pragma unroll
      for (int tt = 0; tt < 5; ++tt) {
        f32x4* p = (f32x4*)&Red[w][tt * 16 + lrow][lkg * 4];
        *p = *p + acc[tt];
      }
    }
    __syncthreads();

    // ---- epilogue: 256 threads, 1 row x 1 col each ----
    if (tid < 256) {
      float s[5];
#pragma unroll
      for (int g5 = 0; g5 < 5; ++g5)
        s[g5] = Red[0][g5 * 16 + ej][rr] + Red[1][g5 * 16 + ej][rr]
              + Red[2][g5 * 16 + ej][rr] + Red[3][g5 * 16 + ej][rr];
      float g_ = 1.f / (1.f + __expf(-(s[0] + bg_b)));
      float r_ = 1.f / (1.f + __expf(-(s[1] + br_b)));
      float z_ = 1.f / (1.f + __expf(-(s[2] + bz_b)));
      float n_ = tanhf(s[3] + bin_b + r_ * (s[4] + bhn_b));
      float h = g_ * ((1.f - z_) * n_ + z_ * hreg);
      hreg = h;
      if (t == SS - 1) out[(size_t)(g * RR + rr) * HH + ghcol] = h;
      else             Hst[rr][ej] = (_Float16)h;
    }

    // ---- publish: wave 0 lanes 0-47, ONE fire-and-forget 16B packet each
    // (768B contiguous, 12 full lines). NO drain, NO flag -- the consumer's
    // tag check replaces both. Barrier also fences Red/Hst WAR (same
    // argument as r12-r15: wave0 rejoins at next reduce barriers).
    if (t < SS - 1) {
      __syncthreads();                 // Hst complete
      if (w == 0 && lane < 48) {
        const int row = lane / 3, s = lane - row * 3;
        uint4v lo = *(const uint4v*)&Hst[row][0];
        uint4v hi = *(const uint4v*)&Hst[row][8];
        uint4v pk = {0u, 0u, 0u, (unsigned)(t + 1)};
        if (s == 0)      { pk[0] = lo[0]; pk[1] = lo[1]; pk[2] = lo[2]; }
        else if (s == 1) { pk[0] = lo[3]; pk[1] = hi[0]; pk[2] = hi[1]; }
        else             { pk[0] = hi[2]; pk[1] = hi[3]; }
        uint4v* dst = Rn + (size_t)cb * PKST + lane;
        asm volatile("global_store_dwordx4 %0, %1, off sc0 sc1" :: "v"(dst), "v"(pk) : "memory");
      }
    }
  }
}

extern "C" void kernel_launch(void* const* d_in, const int* in_sizes, int n_in,
                              void* d_out, int out_size, void* d_ws, size_t ws_size,
                              hipStream_t stream) {
  const float* x   = (const float*)d_in[0];
  const float* Wg  = (const float*)d_in[1];
  const float* bg  = (const float*)d_in[2];
  const float* Wih = (const float*)d_in[3];
  const float* bih = (const float*)d_in[4];
  const float* Whh = (const float*)d_in[5];
  const float* bhh = (const float*)d_in[6];
  // d_in[7..10] (Wa, ba, Ws, bs) are mathematically dead: softmax over size-1 axis == 1
  float* out = (float*)d_out;

  char* ws = (char*)d_ws;
  _Float16* Wp = (_Float16*)ws;                        // 15,728,640 B
  _Float16* Xh = (_Float16*)(ws + 15728640);           // 33,554,432 B
  uint4v*   Pk = (uint4v*)(ws + 15728640 + 33554432);  // 4*2*64*48*16 = 393,216 B

  // Zero both parities every launch: tag 0 == valid zero h(0) for t=0; a
  // stale tag from a previous replay can never equal want=t>0 after the wipe.
  hipMemsetAsync((void*)Pk, 0, 393216, stream);
  prep_w<<<5120, 256, 0, stream>>>(Wg, Wih, Whh, Wp);
  prep_xh<<<dim3(512, 16), 256, 0, stream>>>(x, Xh);
  rnn_seq<<<256, 512, 0, stream>>>(Xh, Wp, bg, bih, bhh, out, Pk);
}